// Round 3
// baseline (395.316 us; speedup 1.0000x reference)
//
#include <hip/hip_runtime.h>

typedef __attribute__((ext_vector_type(8))) short short8;
typedef __attribute__((ext_vector_type(4))) float f32x4;
typedef __attribute__((ext_vector_type(4))) unsigned short u16x4;
typedef __attribute__((ext_vector_type(8))) unsigned short u16x8;

#define H 112
#define W 112
#define HP 114
#define WP 114
#define CIN 128
#define COUT 256
#define NPIX (H * W)          // 12544
#define NIMG 32
#define MTOT (NIMG * NPIX)    // 401408
#define PADELEMS ((long)NIMG * HP * WP * CIN)  // 53,231,616
#define NKT 18                // K-tiles: 9 taps x 2 cin-halves of 64

__device__ __forceinline__ unsigned short f2bf(float f) {
    unsigned int u = __builtin_bit_cast(unsigned int, f);
    u += 0x7FFFu + ((u >> 16) & 1u);
    return (unsigned short)(u >> 16);
}

__device__ __forceinline__ void gl2lds16(const void* g, void* l) {
    __builtin_amdgcn_global_load_lds(
        (const __attribute__((address_space(1))) unsigned int*)g,
        (__attribute__((address_space(3))) unsigned int*)l,
        16, 0, 0);
}

// ---- weights: bf16 {+1,-1}, layout [tap][khalf][cout][cin64] ----
__global__ void binw2_kernel(const float* __restrict__ kw, unsigned short* __restrict__ bw) {
    int tid = blockIdx.x * 256 + threadIdx.x;
    int c    = tid & 63;
    int cout = (tid >> 6) & 255;
    int kh   = (tid >> 14) & 1;
    int tap  = tid >> 15;
    int cin  = kh * 64 + c;
    float w = kw[(tap * 128 + cin) * 256 + cout];
    bw[tid] = (w >= 0.0f) ? (unsigned short)0x3F80u : (unsigned short)0xBF80u;
}

// ---- x (f32 NHWC) -> zero-padded bf16 [N][114][114][128] ----
__global__ void pad_kernel(const float* __restrict__ x, unsigned short* __restrict__ xp) {
    long tid = (long)blockIdx.x * 256 + threadIdx.x;   // one thread = 8 elems
    if (tid >= PADELEMS / 8) return;
    int c8 = (int)(tid & 15);
    long rem = tid >> 4;
    int wp = (int)(rem % WP); rem /= WP;
    int hp = (int)(rem % HP);
    int n  = (int)(rem / HP);
    u16x8 v = {0, 0, 0, 0, 0, 0, 0, 0};
    if (hp >= 1 && hp <= H && wp >= 1 && wp <= W) {
        const float* s = x + (((long)(n * H + hp - 1) * W + (wp - 1)) * CIN + c8 * 8);
        f32x4 a = *(const f32x4*)s;
        f32x4 b = *(const f32x4*)(s + 4);
        v = (u16x8){ f2bf(a.x), f2bf(a.y), f2bf(a.z), f2bf(a.w),
                     f2bf(b.x), f2bf(b.y), f2bf(b.z), f2bf(b.w) };
    }
    *(u16x8*)(xp + tid * 8) = v;
}

// ---- 256x256 deep-pipelined implicit GEMM ----
// 8 waves (2M x 4N), BK=64, double-buffered swizzled LDS, counted vmcnt.
__global__ __launch_bounds__(512, 2)
void conv3_kernel(const unsigned short* __restrict__ xp, const unsigned short* __restrict__ bw,
                  float* __restrict__ out) {
    __shared__ unsigned short As[2][256 * 64];  // 2 x 32KB
    __shared__ unsigned short Bs[2][256 * 64];  // 2 x 32KB

    const int tid = threadIdx.x;
    const int bm = (blockIdx.x & 7) * 196 + (blockIdx.x >> 3);  // XCD swizzle, 1568=8*196
    const int lane = tid & 63;
    const int wv = tid >> 6;
    const int wr = wv >> 2;   // 0..1
    const int wc = wv & 3;    // 0..3

    // ---- staging coords: slot s = tid + j*512; row = s>>3; physical col8 = s&7 ----
    const int r0 = tid >> 3;                      // 0..63 (+ j*64)
    const int c8 = (tid & 7) ^ (r0 & 7);          // pre-swizzled logical col-group
    long apix[4];
#pragma unroll
    for (int j = 0; j < 4; ++j) {
        int row = r0 + j * 64;
        int p = bm * 256 + row;
        int n = p / NPIX;
        int rem = p - n * NPIX;
        int oh = rem / W, ow = rem - oh * W;
        apix[j] = (long)((n * HP + oh + 1) * WP + (ow + 1)) * CIN;
    }

#define STAGE(T1, BUF) do {                                                     \
        const int _tap = (T1) >> 1, _kh = (T1) & 1;                             \
        const long _sh = (long)((_tap / 3 - 1) * WP + (_tap % 3 - 1)) * CIN     \
                         + _kh * 64 + c8 * 8;                                   \
        const unsigned short* _bb = bw + ((_tap * 2 + _kh) << 14)               \
                                    + r0 * 64 + c8 * 8;                         \
        _Pragma("unroll")                                                       \
        for (int j = 0; j < 4; ++j)                                             \
            gl2lds16(xp + apix[j] + _sh, &As[BUF][(j * 512 + wv * 64) * 8]);    \
        _Pragma("unroll")                                                       \
        for (int j = 0; j < 4; ++j)                                             \
            gl2lds16(_bb + j * 4096, &Bs[BUF][(j * 512 + wv * 64) * 8]);        \
    } while (0)

    // ---- fragment read coords (logical byte ^ ((row&7)<<4)) ----
    const int l15 = lane & 15;
    const int lq16 = (lane >> 4) * 16;            // byte offset of k-quarter
    const int arow0 = wr * 128 + l15;
    const int aswz = (arow0 & 7) << 4;
    const int abase = arow0 * 128 + lq16;         // + m*2048 + kk*64, then ^aswz
    const int brow0 = wc * 64 + l15;
    const int bswz = (brow0 & 7) << 4;
    const int bbase = brow0 * 128 + lq16;

    f32x4 acc[8][4];
#pragma unroll
    for (int m = 0; m < 8; ++m)
#pragma unroll
        for (int n = 0; n < 4; ++n)
            acc[m][n] = (f32x4){0.f, 0.f, 0.f, 0.f};

    STAGE(0, 0);   // prologue: tile 0 in flight

    short8 bfrag[4][2];
    for (int t = 0; t < NKT; ++t) {
        const int cur = t & 1;
        if (t < NKT - 1) {
            STAGE(t + 1, cur ^ 1);
            asm volatile("s_waitcnt vmcnt(8)" ::: "memory");  // tile t resident, t+1 in flight
        } else {
            asm volatile("s_waitcnt vmcnt(0)" ::: "memory");
        }
        __builtin_amdgcn_s_barrier();   // all waves' tile-t loads landed

        const char* ab = (const char*)&As[cur][0];
        const char* bb = (const char*)&Bs[cur][0];
#pragma unroll
        for (int p = 0; p < 4; ++p) {
            if (p == 0) {
#pragma unroll
                for (int n = 0; n < 4; ++n)
#pragma unroll
                    for (int kk = 0; kk < 2; ++kk)
                        bfrag[n][kk] = *(const short8*)(bb + ((bbase + n * 2048 + kk * 64) ^ bswz));
            }
            short8 afr[2][2];
#pragma unroll
            for (int mi = 0; mi < 2; ++mi)
#pragma unroll
                for (int kk = 0; kk < 2; ++kk)
                    afr[mi][kk] = *(const short8*)(ab + ((abase + (2 * p + mi) * 2048 + kk * 64) ^ aswz));

            __builtin_amdgcn_s_setprio(1);
#pragma unroll
            for (int mi = 0; mi < 2; ++mi)
#pragma unroll
                for (int n = 0; n < 4; ++n)
#pragma unroll
                    for (int kk = 0; kk < 2; ++kk)
                        acc[2 * p + mi][n] = __builtin_amdgcn_mfma_f32_16x16x32_bf16(
                            afr[mi][kk], bfrag[n][kk], acc[2 * p + mi][n], 0, 0, 0);
            __builtin_amdgcn_s_setprio(0);
            __builtin_amdgcn_s_barrier();   // phase lockstep; last one protects buf reuse
        }
    }
#undef STAGE

    // ---- epilogue: C/D layout col=lane&15, row=(lane>>4)*4+j ----
    const long row0 = (long)bm * 256 + wr * 128 + (lane >> 4) * 4;
    const int col = wc * 64 + (lane & 15);
#pragma unroll
    for (int m = 0; m < 8; ++m)
#pragma unroll
        for (int n = 0; n < 4; ++n)
#pragma unroll
            for (int j = 0; j < 4; ++j)
                out[(row0 + m * 16 + j) * COUT + col + n * 16] = acc[m][n][j];
}

// ---------------- fallback (round-1) path: needs no big workspace ----------------
__global__ void binw_kernel(const float* __restrict__ kw, unsigned short* __restrict__ bw) {
    int tid = blockIdx.x * 256 + threadIdx.x;
    int cin5 = tid & 31;
    int cout = (tid >> 5) & 255;
    int kc4  = (tid >> 13) & 3;
    int tap  = tid >> 15;
    int cin  = kc4 * 32 + cin5;
    float w = kw[(tap * 128 + cin) * 256 + cout];
    bw[tid] = (w >= 0.0f) ? (unsigned short)0x3F80u : (unsigned short)0xBF80u;
}

__global__ __launch_bounds__(256, 2)
void conv_fallback_kernel(const float* __restrict__ x, const unsigned short* __restrict__ bw,
                          float* __restrict__ out) {
    __shared__ unsigned short As[128][40];
    __shared__ unsigned short Bs[128][40];
    const int tid = threadIdx.x;
    const int bm = blockIdx.x, bn = blockIdx.y;
    const int lane = tid & 63;
    const int wv = tid >> 6;
    const int wr = wv >> 1, wc = wv & 1;
    const int c4 = (tid & 7) * 4;
    const int rseg = tid >> 3;
    int ohs[4], ows[4], bases[4];
#pragma unroll
    for (int i = 0; i < 4; ++i) {
        int p = bm * 128 + rseg + i * 32;
        int n = p / NPIX;
        int rem = p - n * NPIX;
        int oh = rem / W, ow = rem - oh * W;
        ohs[i] = oh; ows[i] = ow;
        bases[i] = ((n * H + oh) * W + ow) * CIN;
    }
    f32x4 acc[4][4];
#pragma unroll
    for (int m = 0; m < 4; ++m)
#pragma unroll
        for (int n = 0; n < 4; ++n)
            acc[m][n] = (f32x4){0.f, 0.f, 0.f, 0.f};
    const int arow = wr * 64 + (lane & 15);
    const int brow = wc * 64 + (lane & 15);
    const int koff = (lane >> 4) * 8;
    for (int tap = 0; tap < 9; ++tap) {
        const int dh = tap / 3 - 1, dw = tap % 3 - 1;
        const int shift = (dh * W + dw) * CIN;
#pragma unroll
        for (int kc = 0; kc < 4; ++kc) {
            __syncthreads();
#pragma unroll
            for (int i = 0; i < 4; ++i) {
                int ih = ohs[i] + dh, iw = ows[i] + dw;
                bool valid = ((unsigned)ih < (unsigned)H) & ((unsigned)iw < (unsigned)W);
                f32x4 v = {0.f, 0.f, 0.f, 0.f};
                if (valid) v = *(const f32x4*)(x + bases[i] + shift + kc * 32 + c4);
                u16x4 s = { f2bf(v.x), f2bf(v.y), f2bf(v.z), f2bf(v.w) };
                *(u16x4*)&As[rseg + i * 32][c4] = s;
            }
            const unsigned short* bp = bw + tap * 32768 + kc * 8192 + bn * 4096;
#pragma unroll
            for (int j = 0; j < 2; ++j) {
                int idx = tid + j * 256;
                *(u16x8*)&Bs[idx >> 2][(idx & 3) * 8] = *(const u16x8*)(bp + (idx >> 2) * 32 + (idx & 3) * 8);
            }
            __syncthreads();
            short8 af[4], bfr[4];
#pragma unroll
            for (int m = 0; m < 4; ++m)
                af[m] = *(const short8*)&As[arow + m * 16][koff];
#pragma unroll
            for (int n = 0; n < 4; ++n)
                bfr[n] = *(const short8*)&Bs[brow + n * 16][koff];
#pragma unroll
            for (int m = 0; m < 4; ++m)
#pragma unroll
                for (int n = 0; n < 4; ++n)
                    acc[m][n] = __builtin_amdgcn_mfma_f32_16x16x32_bf16(af[m], bfr[n], acc[m][n], 0, 0, 0);
        }
    }
    const long row0 = (long)bm * 128 + wr * 64 + ((lane >> 4) * 4);
    const int col = bn * 128 + wc * 64 + (lane & 15);
#pragma unroll
    for (int m = 0; m < 4; ++m)
#pragma unroll
        for (int n = 0; n < 4; ++n)
#pragma unroll
            for (int j = 0; j < 4; ++j)
                out[(row0 + m * 16 + j) * COUT + col + n * 16] = acc[m][n][j];
}

extern "C" void kernel_launch(void* const* d_in, const int* in_sizes, int n_in,
                              void* d_out, int out_size, void* d_ws, size_t ws_size,
                              hipStream_t stream) {
    const float* x  = (const float*)d_in[0];
    const float* kw = (const float*)d_in[1];
    float* out = (float*)d_out;
    unsigned short* bw = (unsigned short*)d_ws;           // 589,824 bytes (both layouts)
    const size_t BW_BYTES = 9 * 2 * 256 * 64 * 2;
    const size_t PAD_BYTES = (size_t)PADELEMS * 2;        // ~106.5 MB

    if (ws_size >= BW_BYTES + PAD_BYTES) {
        binw2_kernel<<<(9 * 2 * 256 * 64) / 256, 256, 0, stream>>>(kw, bw);
        unsigned short* xp = (unsigned short*)((char*)d_ws + BW_BYTES);
        pad_kernel<<<(int)((PADELEMS / 8 + 255) / 256), 256, 0, stream>>>(x, xp);
        conv3_kernel<<<MTOT / 256, 512, 0, stream>>>(xp, bw, out);
    } else {
        binw_kernel<<<(9 * 256 * 128) / 256, 256, 0, stream>>>(kw, bw);
        dim3 grid(MTOT / 128, COUT / 128);
        conv_fallback_kernel<<<grid, 256, 0, stream>>>(x, bw, out);
    }
}

// Round 4
// 360.103 us; speedup vs baseline: 1.0978x; 1.0978x over previous
//
#include <hip/hip_runtime.h>

typedef __attribute__((ext_vector_type(8))) short short8;
typedef __attribute__((ext_vector_type(4))) float f32x4;
typedef __attribute__((ext_vector_type(4))) unsigned short u16x4;
typedef __attribute__((ext_vector_type(8))) unsigned short u16x8;

#define H 112
#define W 112
#define HP 114
#define WP 114
#define CIN 128
#define COUT 256
#define NPIX (H * W)          // 12544
#define NIMG 32
#define MTOT (NIMG * NPIX)    // 401408
#define PADELEMS ((long)NIMG * HP * WP * CIN)  // 53,231,616
#define NKT 18                // K-tiles: 9 taps x 2 cin-halves of 64

__device__ __forceinline__ unsigned short f2bf(float f) {
    unsigned int u = __builtin_bit_cast(unsigned int, f);
    u += 0x7FFFu + ((u >> 16) & 1u);
    return (unsigned short)(u >> 16);
}

__device__ __forceinline__ void gl2lds16(const void* g, void* l) {
    __builtin_amdgcn_global_load_lds(
        (const __attribute__((address_space(1))) unsigned int*)g,
        (__attribute__((address_space(3))) unsigned int*)l,
        16, 0, 0);
}

// ---- weights: bf16 {+1,-1}, layout [tap][khalf][cout][cin64] ----
__global__ void binw2_kernel(const float* __restrict__ kw, unsigned short* __restrict__ bw) {
    int tid = blockIdx.x * 256 + threadIdx.x;
    int c    = tid & 63;
    int cout = (tid >> 6) & 255;
    int kh   = (tid >> 14) & 1;
    int tap  = tid >> 15;
    int cin  = kh * 64 + c;
    float w = kw[(tap * 128 + cin) * 256 + cout];
    bw[tid] = (w >= 0.0f) ? (unsigned short)0x3F80u : (unsigned short)0xBF80u;
}

// ---- x (f32 NHWC) -> zero-padded bf16 [N][114][114][128] ----
__global__ void pad_kernel(const float* __restrict__ x, unsigned short* __restrict__ xp) {
    long tid = (long)blockIdx.x * 256 + threadIdx.x;   // one thread = 8 elems
    if (tid >= PADELEMS / 8) return;
    int c8 = (int)(tid & 15);
    long rem = tid >> 4;
    int wp = (int)(rem % WP); rem /= WP;
    int hp = (int)(rem % HP);
    int n  = (int)(rem / HP);
    u16x8 v = {0, 0, 0, 0, 0, 0, 0, 0};
    if (hp >= 1 && hp <= H && wp >= 1 && wp <= W) {
        const float* s = x + (((long)(n * H + hp - 1) * W + (wp - 1)) * CIN + c8 * 8);
        f32x4 a = *(const f32x4*)s;
        f32x4 b = *(const f32x4*)(s + 4);
        v = (u16x8){ f2bf(a.x), f2bf(a.y), f2bf(a.z), f2bf(a.w),
                     f2bf(b.x), f2bf(b.y), f2bf(b.z), f2bf(b.w) };
    }
    *(u16x8*)(xp + tid * 8) = v;
}

// ---- 256x256 implicit GEMM, m201-style 4-phase/K-tile interleaved schedule ----
// 8 waves (2M x 4N), BK=64, double-buffered swizzled LDS, counted vmcnt(2)/K-tile.
__global__ __launch_bounds__(512, 2)
void conv4_kernel(const unsigned short* __restrict__ xp, const unsigned short* __restrict__ bw,
                  float* __restrict__ out) {
    __shared__ unsigned short As[2][256 * 64];  // 2 x 32KB
    __shared__ unsigned short Bs[2][256 * 64];  // 2 x 32KB

    const int tid = threadIdx.x;
    const int bm = (blockIdx.x & 7) * 196 + (blockIdx.x >> 3);  // XCD swizzle, 1568=8*196
    const int lane = tid & 63;
    const int wv = tid >> 6;
    const int wr = wv >> 2;   // 0..1
    const int wc = wv & 3;    // 0..3

    // staging coords: slot s = tid + j*512; row = s>>3; physical col8 = tid&7
    const int r0 = tid >> 3;                      // 0..63 (+ j*64)
    const int c8 = (tid & 7) ^ (r0 & 7);          // pre-swizzled logical col-group
    long apix[4];
#pragma unroll
    for (int j = 0; j < 4; ++j) {
        int row = r0 + j * 64;
        int p = bm * 256 + row;
        int n = p / NPIX;
        int rem = p - n * NPIX;
        int oh = rem / W, ow = rem - oh * W;
        apix[j] = (long)((n * HP + oh + 1) * WP + (ow + 1)) * CIN;
    }

    // stage half-tile J (A rows [J*64,J*64+64) + B rows likewise) of K-tile T1 into BUF
#define STAGE_HALF(T1, BUF, J) do {                                             \
        const int _tap = (T1) >> 1, _kh = (T1) & 1;                             \
        const long _sh = (long)((_tap / 3 - 1) * WP + (_tap % 3 - 1)) * CIN     \
                         + _kh * 64 + c8 * 8;                                   \
        gl2lds16(xp + apix[J] + _sh, &As[BUF][((J) * 512 + wv * 64) * 8]);      \
        gl2lds16(bw + ((_tap * 2 + _kh) << 14) + r0 * 64 + c8 * 8 + (J) * 4096, \
                 &Bs[BUF][((J) * 512 + wv * 64) * 8]);                          \
    } while (0)

    // fragment read coords (logical byte ^ ((row&7)<<4))
    const int l15 = lane & 15;
    const int lq16 = (lane >> 4) * 16;            // byte offset of k-quarter
    const int arow0 = wr * 128 + l15;
    const int aswz = (arow0 & 7) << 4;
    const int abase = arow0 * 128 + lq16;         // + m*2048 + kk*64, then ^aswz
    const int brow0 = wc * 64 + l15;
    const int bswz = (brow0 & 7) << 4;
    const int bbase = brow0 * 128 + lq16;

    f32x4 acc[8][4];
#pragma unroll
    for (int m = 0; m < 8; ++m)
#pragma unroll
        for (int n = 0; n < 4; ++n)
            acc[m][n] = (f32x4){0.f, 0.f, 0.f, 0.f};

    // prologue: K-tile 0 fully in flight (8 loads)
    STAGE_HALF(0, 0, 0);
    STAGE_HALF(0, 0, 1);
    STAGE_HALF(0, 0, 2);
    STAGE_HALF(0, 0, 3);

    for (int t = 0; t < NKT - 1; ++t) {
        const int cur = t & 1;
        const int nxt = cur ^ 1;
        const char* ab = (const char*)&As[cur][0];
        const char* bb = (const char*)&Bs[cur][0];
        short8 bfrag[4][2];
#pragma unroll
        for (int p = 0; p < 4; ++p) {
            short8 afr[2][2];
            if (p == 0) {
                STAGE_HALF(t + 1, nxt, 0);
                asm volatile("s_waitcnt vmcnt(2)" ::: "memory");  // tile t resident
                __builtin_amdgcn_s_barrier();
#pragma unroll
                for (int n = 0; n < 4; ++n)
#pragma unroll
                    for (int kk = 0; kk < 2; ++kk)
                        bfrag[n][kk] = *(const short8*)(bb + ((bbase + n * 2048 + kk * 64) ^ bswz));
#pragma unroll
                for (int mi = 0; mi < 2; ++mi)
#pragma unroll
                    for (int kk = 0; kk < 2; ++kk)
                        afr[mi][kk] = *(const short8*)(ab + ((abase + mi * 2048 + kk * 64) ^ aswz));
            } else {
#pragma unroll
                for (int mi = 0; mi < 2; ++mi)
#pragma unroll
                    for (int kk = 0; kk < 2; ++kk)
                        afr[mi][kk] = *(const short8*)(ab + ((abase + (2 * p + mi) * 2048 + kk * 64) ^ aswz));
                STAGE_HALF(t + 1, nxt, p);   // one half-tile prefetch per phase
                __builtin_amdgcn_s_barrier();
            }
            asm volatile("s_waitcnt lgkmcnt(0)" ::: "memory");
            __builtin_amdgcn_sched_barrier(0);
            __builtin_amdgcn_s_setprio(1);
#pragma unroll
            for (int mi = 0; mi < 2; ++mi)
#pragma unroll
                for (int n = 0; n < 4; ++n)
#pragma unroll
                    for (int kk = 0; kk < 2; ++kk)
                        acc[2 * p + mi][n] = __builtin_amdgcn_mfma_f32_16x16x32_bf16(
                            afr[mi][kk], bfrag[n][kk], acc[2 * p + mi][n], 0, 0, 0);
            __builtin_amdgcn_s_setprio(0);
            __builtin_amdgcn_s_barrier();
        }
    }

    // ---- peeled last K-tile (no stages, no per-phase barriers needed) ----
    {
        const int cur = (NKT - 1) & 1;
        const char* ab = (const char*)&As[cur][0];
        const char* bb = (const char*)&Bs[cur][0];
        asm volatile("s_waitcnt vmcnt(0)" ::: "memory");
        __builtin_amdgcn_s_barrier();
        short8 bfrag[4][2];
#pragma unroll
        for (int n = 0; n < 4; ++n)
#pragma unroll
            for (int kk = 0; kk < 2; ++kk)
                bfrag[n][kk] = *(const short8*)(bb + ((bbase + n * 2048 + kk * 64) ^ bswz));
#pragma unroll
        for (int p = 0; p < 4; ++p) {
            short8 afr[2][2];
#pragma unroll
            for (int mi = 0; mi < 2; ++mi)
#pragma unroll
                for (int kk = 0; kk < 2; ++kk)
                    afr[mi][kk] = *(const short8*)(ab + ((abase + (2 * p + mi) * 2048 + kk * 64) ^ aswz));
#pragma unroll
            for (int mi = 0; mi < 2; ++mi)
#pragma unroll
                for (int n = 0; n < 4; ++n)
#pragma unroll
                    for (int kk = 0; kk < 2; ++kk)
                        acc[2 * p + mi][n] = __builtin_amdgcn_mfma_f32_16x16x32_bf16(
                            afr[mi][kk], bfrag[n][kk], acc[2 * p + mi][n], 0, 0, 0);
        }
    }
#undef STAGE_HALF

    // ---- epilogue: C/D layout col=lane&15, row=(lane>>4)*4+j ----
    const long row0 = (long)bm * 256 + wr * 128 + (lane >> 4) * 4;
    const int col = wc * 64 + (lane & 15);
#pragma unroll
    for (int m = 0; m < 8; ++m)
#pragma unroll
        for (int n = 0; n < 4; ++n)
#pragma unroll
            for (int j = 0; j < 4; ++j)
                out[(row0 + m * 16 + j) * COUT + col + n * 16] = acc[m][n][j];
}

// ---------------- fallback (round-1) path: needs no big workspace ----------------
__global__ void binw_kernel(const float* __restrict__ kw, unsigned short* __restrict__ bw) {
    int tid = blockIdx.x * 256 + threadIdx.x;
    int cin5 = tid & 31;
    int cout = (tid >> 5) & 255;
    int kc4  = (tid >> 13) & 3;
    int tap  = tid >> 15;
    int cin  = kc4 * 32 + cin5;
    float w = kw[(tap * 128 + cin) * 256 + cout];
    bw[tid] = (w >= 0.0f) ? (unsigned short)0x3F80u : (unsigned short)0xBF80u;
}

__global__ __launch_bounds__(256, 2)
void conv_fallback_kernel(const float* __restrict__ x, const unsigned short* __restrict__ bw,
                          float* __restrict__ out) {
    __shared__ unsigned short As[128][40];
    __shared__ unsigned short Bs[128][40];
    const int tid = threadIdx.x;
    const int bm = blockIdx.x, bn = blockIdx.y;
    const int lane = tid & 63;
    const int wv = tid >> 6;
    const int wr = wv >> 1, wc = wv & 1;
    const int c4 = (tid & 7) * 4;
    const int rseg = tid >> 3;
    int ohs[4], ows[4], bases[4];
#pragma unroll
    for (int i = 0; i < 4; ++i) {
        int p = bm * 128 + rseg + i * 32;
        int n = p / NPIX;
        int rem = p - n * NPIX;
        int oh = rem / W, ow = rem - oh * W;
        ohs[i] = oh; ows[i] = ow;
        bases[i] = ((n * H + oh) * W + ow) * CIN;
    }
    f32x4 acc[4][4];
#pragma unroll
    for (int m = 0; m < 4; ++m)
#pragma unroll
        for (int n = 0; n < 4; ++n)
            acc[m][n] = (f32x4){0.f, 0.f, 0.f, 0.f};
    const int arow = wr * 64 + (lane & 15);
    const int brow = wc * 64 + (lane & 15);
    const int koff = (lane >> 4) * 8;
    for (int tap = 0; tap < 9; ++tap) {
        const int dh = tap / 3 - 1, dw = tap % 3 - 1;
        const int shift = (dh * W + dw) * CIN;
#pragma unroll
        for (int kc = 0; kc < 4; ++kc) {
            __syncthreads();
#pragma unroll
            for (int i = 0; i < 4; ++i) {
                int ih = ohs[i] + dh, iw = ows[i] + dw;
                bool valid = ((unsigned)ih < (unsigned)H) & ((unsigned)iw < (unsigned)W);
                f32x4 v = {0.f, 0.f, 0.f, 0.f};
                if (valid) v = *(const f32x4*)(x + bases[i] + shift + kc * 32 + c4);
                u16x4 s = { f2bf(v.x), f2bf(v.y), f2bf(v.z), f2bf(v.w) };
                *(u16x4*)&As[rseg + i * 32][c4] = s;
            }
            const unsigned short* bp = bw + tap * 32768 + kc * 8192 + bn * 4096;
#pragma unroll
            for (int j = 0; j < 2; ++j) {
                int idx = tid + j * 256;
                *(u16x8*)&Bs[idx >> 2][(idx & 3) * 8] = *(const u16x8*)(bp + (idx >> 2) * 32 + (idx & 3) * 8);
            }
            __syncthreads();
            short8 af[4], bfr[4];
#pragma unroll
            for (int m = 0; m < 4; ++m)
                af[m] = *(const short8*)&As[arow + m * 16][koff];
#pragma unroll
            for (int n = 0; n < 4; ++n)
                bfr[n] = *(const short8*)&Bs[brow + n * 16][koff];
#pragma unroll
            for (int m = 0; m < 4; ++m)
#pragma unroll
                for (int n = 0; n < 4; ++n)
                    acc[m][n] = __builtin_amdgcn_mfma_f32_16x16x32_bf16(af[m], bfr[n], acc[m][n], 0, 0, 0);
        }
    }
    const long row0 = (long)bm * 128 + wr * 64 + ((lane >> 4) * 4);
    const int col = bn * 128 + wc * 64 + (lane & 15);
#pragma unroll
    for (int m = 0; m < 4; ++m)
#pragma unroll
        for (int n = 0; n < 4; ++n)
#pragma unroll
            for (int j = 0; j < 4; ++j)
                out[(row0 + m * 16 + j) * COUT + col + n * 16] = acc[m][n][j];
}

extern "C" void kernel_launch(void* const* d_in, const int* in_sizes, int n_in,
                              void* d_out, int out_size, void* d_ws, size_t ws_size,
                              hipStream_t stream) {
    const float* x  = (const float*)d_in[0];
    const float* kw = (const float*)d_in[1];
    float* out = (float*)d_out;
    unsigned short* bw = (unsigned short*)d_ws;
    const size_t BW_BYTES = 9 * 2 * 256 * 64 * 2;         // 589,824
    const size_t PAD_BYTES = (size_t)PADELEMS * 2;        // ~106.5 MB

    if (ws_size >= BW_BYTES + PAD_BYTES) {
        binw2_kernel<<<(9 * 2 * 256 * 64) / 256, 256, 0, stream>>>(kw, bw);
        unsigned short* xp = (unsigned short*)((char*)d_ws + BW_BYTES);
        pad_kernel<<<(int)((PADELEMS / 8 + 255) / 256), 256, 0, stream>>>(x, xp);
        conv4_kernel<<<MTOT / 256, 512, 0, stream>>>(xp, bw, out);
    } else {
        binw_kernel<<<(9 * 256 * 128) / 256, 256, 0, stream>>>(kw, bw);
        dim3 grid(MTOT / 128, COUT / 128);
        conv_fallback_kernel<<<grid, 256, 0, stream>>>(x, bw, out);
    }
}

// Round 5
// 342.634 us; speedup vs baseline: 1.1538x; 1.0510x over previous
//
#include <hip/hip_runtime.h>

typedef __attribute__((ext_vector_type(8))) short short8;
typedef __attribute__((ext_vector_type(4))) float f32x4;
typedef __attribute__((ext_vector_type(4))) unsigned short u16x4;
typedef __attribute__((ext_vector_type(8))) unsigned short u16x8;

#define H 112
#define W 112
#define HP 114
#define WP 114
#define CIN 128
#define COUT 256
#define NPIX (H * W)          // 12544
#define NIMG 32
#define MTOT (NIMG * NPIX)    // 401408
#define PADELEMS ((long)NIMG * HP * WP * CIN)  // 53,231,616
#define NKT 18                // K-tiles: 9 taps x 2 cin-halves of 64

__device__ __forceinline__ unsigned short f2bf(float f) {
    unsigned int u = __builtin_bit_cast(unsigned int, f);
    u += 0x7FFFu + ((u >> 16) & 1u);
    return (unsigned short)(u >> 16);
}

__device__ __forceinline__ void gl2lds16(const void* g, void* l) {
    __builtin_amdgcn_global_load_lds(
        (const __attribute__((address_space(1))) unsigned int*)g,
        (__attribute__((address_space(3))) unsigned int*)l,
        16, 0, 0);
}

// ---- weights: bf16 {+1,-1}, layout [tap][khalf][cout][cin64] ----
__global__ void binw2_kernel(const float* __restrict__ kw, unsigned short* __restrict__ bw) {
    int tid = blockIdx.x * 256 + threadIdx.x;
    int c    = tid & 63;
    int cout = (tid >> 6) & 255;
    int kh   = (tid >> 14) & 1;
    int tap  = tid >> 15;
    int cin  = kh * 64 + c;
    float w = kw[(tap * 128 + cin) * 256 + cout];
    bw[tid] = (w >= 0.0f) ? (unsigned short)0x3F80u : (unsigned short)0xBF80u;
}

// ---- x (f32 NHWC) -> zero-padded bf16 [N][114][114][128] ----
__global__ void pad_kernel(const float* __restrict__ x, unsigned short* __restrict__ xp) {
    long tid = (long)blockIdx.x * 256 + threadIdx.x;   // one thread = 8 elems
    if (tid >= PADELEMS / 8) return;
    int c8 = (int)(tid & 15);
    long rem = tid >> 4;
    int wp = (int)(rem % WP); rem /= WP;
    int hp = (int)(rem % HP);
    int n  = (int)(rem / HP);
    u16x8 v = {0, 0, 0, 0, 0, 0, 0, 0};
    if (hp >= 1 && hp <= H && wp >= 1 && wp <= W) {
        const float* s = x + (((long)(n * H + hp - 1) * W + (wp - 1)) * CIN + c8 * 8);
        f32x4 a = *(const f32x4*)s;
        f32x4 b = *(const f32x4*)(s + 4);
        v = (u16x8){ f2bf(a.x), f2bf(a.y), f2bf(a.z), f2bf(a.w),
                     f2bf(b.x), f2bf(b.y), f2bf(b.z), f2bf(b.w) };
    }
    *(u16x8*)(xp + tid * 8) = v;
}

// ---- 128x128 implicit GEMM, 2 blocks/CU, counted-vmcnt 2-phase/K-tile ----
// 4 waves (2M x 2N), per-wave 64x64, BK=64, double-buffered swizzled LDS (64KiB).
__global__ __launch_bounds__(256, 2)
void conv5_kernel(const unsigned short* __restrict__ xp, const unsigned short* __restrict__ bw,
                  float* __restrict__ out) {
    __shared__ unsigned short As[2][128 * 64];  // 2 x 16KB
    __shared__ unsigned short Bs[2][128 * 64];  // 2 x 16KB

    const int tid = threadIdx.x;
    const int swz = (blockIdx.x & 7) * 784 + (blockIdx.x >> 3);  // 6272 = 8*784, bijective
    const int bm = swz >> 1;       // 0..3135 (consecutive ids share bm -> same XCD)
    const int bn = swz & 1;        // 0..1
    const int lane = tid & 63;
    const int wv = tid >> 6;       // 0..3
    const int wr = wv >> 1, wc = wv & 1;

    // staging coords: slot s = tid + J*256; row = s>>3 = r0 + J*32; phys col8 = tid&7
    const int r0 = tid >> 3;                      // 0..31
    const int c8 = (tid & 7) ^ (r0 & 7);          // pre-swizzled logical col-group
    long apix[4];
#pragma unroll
    for (int j = 0; j < 4; ++j) {
        int row = r0 + j * 32;
        int p = bm * 128 + row;
        int n = p / NPIX;
        int rem = p - n * NPIX;
        int oh = rem / W, ow = rem - oh * W;
        apix[j] = (long)((n * HP + oh + 1) * WP + (ow + 1)) * CIN;
    }

    // stage slot-group J (A rows [J*32,J*32+32) + B rows likewise) of K-tile T1 into BUF
#define STAGE_J(T1, BUF, J) do {                                                \
        const int _tap = (T1) >> 1, _kh = (T1) & 1;                             \
        const long _sh = (long)((_tap / 3 - 1) * WP + (_tap % 3 - 1)) * CIN     \
                         + _kh * 64 + c8 * 8;                                   \
        gl2lds16(xp + apix[J] + _sh, &As[BUF][((J) * 256 + wv * 64) * 8]);      \
        gl2lds16(bw + ((_tap * 2 + _kh) << 14) + bn * 8192                      \
                    + (r0 + (J) * 32) * 64 + c8 * 8,                            \
                 &Bs[BUF][((J) * 256 + wv * 64) * 8]);                          \
    } while (0)

    // fragment read coords (logical byte ^ ((row&7)<<4); row&7 == l15&7, m*16 preserves it)
    const int l15 = lane & 15;
    const int lq16 = (lane >> 4) * 16;            // byte offset of k-quarter
    const int arow0 = wr * 64 + l15;
    const int aswz = (arow0 & 7) << 4;
    const int abase = arow0 * 128 + lq16;         // + m*2048 + kk*64, then ^aswz
    const int brow0 = wc * 64 + l15;
    const int bswz = (brow0 & 7) << 4;
    const int bbase = brow0 * 128 + lq16;

    f32x4 acc[4][4];
#pragma unroll
    for (int m = 0; m < 4; ++m)
#pragma unroll
        for (int n = 0; n < 4; ++n)
            acc[m][n] = (f32x4){0.f, 0.f, 0.f, 0.f};

    // prologue: K-tile 0 fully in flight (8 loads)
    STAGE_J(0, 0, 0);
    STAGE_J(0, 0, 1);
    STAGE_J(0, 0, 2);
    STAGE_J(0, 0, 3);

    for (int t = 0; t < NKT - 1; ++t) {
        const int cur = t & 1;
        const int nxt = cur ^ 1;
        const char* ab = (const char*)&As[cur][0];
        const char* bb = (const char*)&Bs[cur][0];
        short8 bfrag[4][2];

        // ---- phase 0: stage J0,J1 of t+1; drain tile t; MFMA m=0,1 ----
        STAGE_J(t + 1, nxt, 0);
        STAGE_J(t + 1, nxt, 1);
        asm volatile("s_waitcnt vmcnt(4)" ::: "memory");  // tile t resident, 4 new in flight
        __builtin_amdgcn_s_barrier();
#pragma unroll
        for (int n = 0; n < 4; ++n)
#pragma unroll
            for (int kk = 0; kk < 2; ++kk)
                bfrag[n][kk] = *(const short8*)(bb + ((bbase + n * 2048 + kk * 64) ^ bswz));
        {
            short8 afr[2][2];
#pragma unroll
            for (int mi = 0; mi < 2; ++mi)
#pragma unroll
                for (int kk = 0; kk < 2; ++kk)
                    afr[mi][kk] = *(const short8*)(ab + ((abase + mi * 2048 + kk * 64) ^ aswz));
            asm volatile("s_waitcnt lgkmcnt(0)" ::: "memory");
            __builtin_amdgcn_sched_barrier(0);
            __builtin_amdgcn_s_setprio(1);
#pragma unroll
            for (int mi = 0; mi < 2; ++mi)
#pragma unroll
                for (int n = 0; n < 4; ++n)
#pragma unroll
                    for (int kk = 0; kk < 2; ++kk)
                        acc[mi][n] = __builtin_amdgcn_mfma_f32_16x16x32_bf16(
                            afr[mi][kk], bfrag[n][kk], acc[mi][n], 0, 0, 0);
            __builtin_amdgcn_s_setprio(0);
            __builtin_amdgcn_s_barrier();
        }

        // ---- phase 1: stage J2,J3 of t+1; MFMA m=2,3 ----
        {
            short8 afr[2][2];
#pragma unroll
            for (int mi = 0; mi < 2; ++mi)
#pragma unroll
                for (int kk = 0; kk < 2; ++kk)
                    afr[mi][kk] = *(const short8*)(ab + ((abase + (2 + mi) * 2048 + kk * 64) ^ aswz));
            STAGE_J(t + 1, nxt, 2);
            STAGE_J(t + 1, nxt, 3);
            __builtin_amdgcn_s_barrier();
            asm volatile("s_waitcnt lgkmcnt(0)" ::: "memory");
            __builtin_amdgcn_sched_barrier(0);
            __builtin_amdgcn_s_setprio(1);
#pragma unroll
            for (int mi = 0; mi < 2; ++mi)
#pragma unroll
                for (int n = 0; n < 4; ++n)
#pragma unroll
                    for (int kk = 0; kk < 2; ++kk)
                        acc[2 + mi][n] = __builtin_amdgcn_mfma_f32_16x16x32_bf16(
                            afr[mi][kk], bfrag[n][kk], acc[2 + mi][n], 0, 0, 0);
            __builtin_amdgcn_s_setprio(0);
            __builtin_amdgcn_s_barrier();   // all reads of buffer cur done -> t+1 may stage into it
        }
    }

    // ---- peeled last K-tile (no stages; compiler-managed lgkm waits) ----
    {
        const int cur = (NKT - 1) & 1;
        const char* ab = (const char*)&As[cur][0];
        const char* bb = (const char*)&Bs[cur][0];
        asm volatile("s_waitcnt vmcnt(0)" ::: "memory");
        __builtin_amdgcn_s_barrier();
        short8 bfrag[4][2];
#pragma unroll
        for (int n = 0; n < 4; ++n)
#pragma unroll
            for (int kk = 0; kk < 2; ++kk)
                bfrag[n][kk] = *(const short8*)(bb + ((bbase + n * 2048 + kk * 64) ^ bswz));
#pragma unroll
        for (int m = 0; m < 4; ++m) {
            short8 afr[2];
#pragma unroll
            for (int kk = 0; kk < 2; ++kk)
                afr[kk] = *(const short8*)(ab + ((abase + m * 2048 + kk * 64) ^ aswz));
#pragma unroll
            for (int n = 0; n < 4; ++n)
#pragma unroll
                for (int kk = 0; kk < 2; ++kk)
                    acc[m][n] = __builtin_amdgcn_mfma_f32_16x16x32_bf16(
                        afr[kk], bfrag[n][kk], acc[m][n], 0, 0, 0);
        }
    }
#undef STAGE_J

    // ---- epilogue: C/D layout col=lane&15, row=(lane>>4)*4+j ----
    const long row0 = (long)bm * 128 + wr * 64 + (lane >> 4) * 4;
    const int col = bn * 128 + wc * 64 + l15;
#pragma unroll
    for (int m = 0; m < 4; ++m)
#pragma unroll
        for (int n = 0; n < 4; ++n)
#pragma unroll
            for (int j = 0; j < 4; ++j)
                out[(row0 + m * 16 + j) * COUT + col + n * 16] = acc[m][n][j];
}

// ---------------- fallback (round-1) path: needs no big workspace ----------------
__global__ void binw_kernel(const float* __restrict__ kw, unsigned short* __restrict__ bw) {
    int tid = blockIdx.x * 256 + threadIdx.x;
    int cin5 = tid & 31;
    int cout = (tid >> 5) & 255;
    int kc4  = (tid >> 13) & 3;
    int tap  = tid >> 15;
    int cin  = kc4 * 32 + cin5;
    float w = kw[(tap * 128 + cin) * 256 + cout];
    bw[tid] = (w >= 0.0f) ? (unsigned short)0x3F80u : (unsigned short)0xBF80u;
}

__global__ __launch_bounds__(256, 2)
void conv_fallback_kernel(const float* __restrict__ x, const unsigned short* __restrict__ bw,
                          float* __restrict__ out) {
    __shared__ unsigned short As[128][40];
    __shared__ unsigned short Bs[128][40];
    const int tid = threadIdx.x;
    const int bm = blockIdx.x, bn = blockIdx.y;
    const int lane = tid & 63;
    const int wv = tid >> 6;
    const int wr = wv >> 1, wc = wv & 1;
    const int c4 = (tid & 7) * 4;
    const int rseg = tid >> 3;
    int ohs[4], ows[4], bases[4];
#pragma unroll
    for (int i = 0; i < 4; ++i) {
        int p = bm * 128 + rseg + i * 32;
        int n = p / NPIX;
        int rem = p - n * NPIX;
        int oh = rem / W, ow = rem - oh * W;
        ohs[i] = oh; ows[i] = ow;
        bases[i] = ((n * H + oh) * W + ow) * CIN;
    }
    f32x4 acc[4][4];
#pragma unroll
    for (int m = 0; m < 4; ++m)
#pragma unroll
        for (int n = 0; n < 4; ++n)
            acc[m][n] = (f32x4){0.f, 0.f, 0.f, 0.f};
    const int arow = wr * 64 + (lane & 15);
    const int brow = wc * 64 + (lane & 15);
    const int koff = (lane >> 4) * 8;
    for (int tap = 0; tap < 9; ++tap) {
        const int dh = tap / 3 - 1, dw = tap % 3 - 1;
        const int shift = (dh * W + dw) * CIN;
#pragma unroll
        for (int kc = 0; kc < 4; ++kc) {
            __syncthreads();
#pragma unroll
            for (int i = 0; i < 4; ++i) {
                int ih = ohs[i] + dh, iw = ows[i] + dw;
                bool valid = ((unsigned)ih < (unsigned)H) & ((unsigned)iw < (unsigned)W);
                f32x4 v = {0.f, 0.f, 0.f, 0.f};
                if (valid) v = *(const f32x4*)(x + bases[i] + shift + kc * 32 + c4);
                u16x4 s = { f2bf(v.x), f2bf(v.y), f2bf(v.z), f2bf(v.w) };
                *(u16x4*)&As[rseg + i * 32][c4] = s;
            }
            const unsigned short* bp = bw + tap * 32768 + kc * 8192 + bn * 4096;
#pragma unroll
            for (int j = 0; j < 2; ++j) {
                int idx = tid + j * 256;
                *(u16x8*)&Bs[idx >> 2][(idx & 3) * 8] = *(const u16x8*)(bp + (idx >> 2) * 32 + (idx & 3) * 8);
            }
            __syncthreads();
            short8 af[4], bfr[4];
#pragma unroll
            for (int m = 0; m < 4; ++m)
                af[m] = *(const short8*)&As[arow + m * 16][koff];
#pragma unroll
            for (int n = 0; n < 4; ++n)
                bfr[n] = *(const short8*)&Bs[brow + n * 16][koff];
#pragma unroll
            for (int m = 0; m < 4; ++m)
#pragma unroll
                for (int n = 0; n < 4; ++n)
                    acc[m][n] = __builtin_amdgcn_mfma_f32_16x16x32_bf16(af[m], bfr[n], acc[m][n], 0, 0, 0);
        }
    }
    const long row0 = (long)bm * 128 + wr * 64 + ((lane >> 4) * 4);
    const int col = bn * 128 + wc * 64 + (lane & 15);
#pragma unroll
    for (int m = 0; m < 4; ++m)
#pragma unroll
        for (int n = 0; n < 4; ++n)
#pragma unroll
            for (int j = 0; j < 4; ++j)
                out[(row0 + m * 16 + j) * COUT + col + n * 16] = acc[m][n][j];
}

extern "C" void kernel_launch(void* const* d_in, const int* in_sizes, int n_in,
                              void* d_out, int out_size, void* d_ws, size_t ws_size,
                              hipStream_t stream) {
    const float* x  = (const float*)d_in[0];
    const float* kw = (const float*)d_in[1];
    float* out = (float*)d_out;
    unsigned short* bw = (unsigned short*)d_ws;
    const size_t BW_BYTES = 9 * 2 * 256 * 64 * 2;         // 589,824
    const size_t PAD_BYTES = (size_t)PADELEMS * 2;        // ~106.5 MB

    if (ws_size >= BW_BYTES + PAD_BYTES) {
        binw2_kernel<<<(9 * 2 * 256 * 64) / 256, 256, 0, stream>>>(kw, bw);
        unsigned short* xp = (unsigned short*)((char*)d_ws + BW_BYTES);
        pad_kernel<<<(int)((PADELEMS / 8 + 255) / 256), 256, 0, stream>>>(x, xp);
        conv5_kernel<<<(MTOT / 128) * 2, 256, 0, stream>>>(xp, bw, out);
    } else {
        binw_kernel<<<(9 * 256 * 128) / 256, 256, 0, stream>>>(kw, bw);
        dim3 grid(MTOT / 128, COUT / 128);
        conv_fallback_kernel<<<grid, 256, 0, stream>>>(x, bw, out);
    }
}